// Round 4
// baseline (405.451 us; speedup 1.0000x reference)
//
#include <hip/hip_runtime.h>

#define DM 1024
#define NSEQ 8192

typedef __attribute__((ext_vector_type(8))) short short8;
typedef __attribute__((ext_vector_type(4))) float floatx4;

// pack two fp32 -> bf16x2 (round-to-nearest via +0x8000), 3 VALU ops
__device__ __forceinline__ unsigned pk_rn(float a, float b) {
  return __builtin_amdgcn_perm(__float_as_uint(b) + 0x8000u,
                               __float_as_uint(a) + 0x8000u, 0x07060302u);
}

// Build V^T for the 128-kk chunk sitting in K buffer `bufsel` (LDS->LDS
// transpose; row-broadcast reads, conflict-light). VT unit u16*64+dp holds
// V^T[d = dp ^ (u16&7)][kk = 8*u16 .. +8] (chunk-local kk).
__device__ __forceinline__ void build_vt(uint4* smem, int tid, int bufsel) {
  const unsigned short* Bs = (const unsigned short*)&smem[bufsel * 1024];
  #pragma unroll
  for (int p = 0; p < 2; ++p) {
    int m = p * 512 + tid;                   // 0..1023
    int u16 = m >> 6, dp = m & 63;
    int d = dp ^ (u16 & 7);
    unsigned v[8];
    #pragma unroll
    for (int j = 0; j < 8; ++j) {
      int kkl = 8 * u16 + j;                 // kkl & 7 == j
      v[j] = Bs[(kkl * 8 + ((d >> 3) ^ j)) * 8 + (d & 7)];
    }
    uint4 pk;
    pk.x = v[0] | (v[1] << 16);
    pk.y = v[2] | (v[3] << 16);
    pk.z = v[4] | (v[5] << 16);
    pk.w = v[6] | (v[7] << 16);
    smem[2048 + m] = pk;
  }
}

// Fused dilated attention, 2 blocks per (b,s,h) tile (each owns 256 q rows).
// 512 thr = 8 waves x 32 q. LDS 64 KB -> 2 blocks/CU, 16 waves/CU:
//   [0,2048)    K chunk double-buffer (2 x 128 rows x 64 cols bf16, swizzled:
//               unit rl*8 + (c8 ^ (rl&7)) holds K[rl][8*c8 .. +8])
//   [2048,3072) VT chunk (see build_vt)
//   [3072,4096) P strips, 128 units per wave
// Chunk pipeline: compute(c) || load K(c+2); barrier; write K(c+2), build
// VT(c+1); barrier. Chunk order rotated per half so Q lives in chunks 0,1.
__global__ __launch_bounds__(512, 4)
void fused2(const float* __restrict__ x, float* __restrict__ out) {
  __shared__ uint4 smem[4096];
  const int g = blockIdx.x;                    // 1024 = tile(512) x half(2)
  const int tau = (g & 7) * 64 + (g >> 4);     // pair (g, g+8) -> same tile, same XCD
  const int half = (g >> 3) & 1;
  const int b = tau >> 7, s = (tau >> 4) & 7, h = tau & 15;
  const float* xb = x + ((size_t)b * NSEQ + s * 1024) * DM + h * 64;
  float* ob = out + ((size_t)b * NSEQ + s * 1024) * DM + h * 64;
  const int qoff = half * 256;
  const int first = half * 2;                  // first chunk = the one holding our q
  const int tid = threadIdx.x;
  const int lane = tid & 63;
  const int wu = __builtin_amdgcn_readfirstlane(tid >> 6);
  const int c8 = tid & 7, rr = tid >> 3;       // rr 0..63

  // ---- prologue: load chunks first, first+1; zero odd rows; stage to LDS ----
  float4 A[4], B[4];
  #pragma unroll
  for (int i = 0; i < 4; ++i) {
    int rl = (i & 1) * 64 + rr;
    int ch = first + (i >> 1);
    const float* src = xb + (size_t)(2 * (128 * ch + rl)) * DM + c8 * 8;
    A[i] = *(const float4*)src;
    B[i] = *(const float4*)(src + 4);
  }
  {
    const float4 z = make_float4(0.f, 0.f, 0.f, 0.f);
    #pragma unroll
    for (int p = 0; p < 4; ++p) {
      int j = qoff + p * 64 + rr;
      float* zp = ob + (size_t)(2 * j + 1) * DM + c8 * 8;
      *(float4*)zp = z;
      *(float4*)(zp + 4) = z;
    }
  }
  #pragma unroll
  for (int i = 0; i < 4; ++i) {
    int rl = (i & 1) * 64 + rr;
    uint4 pk;
    pk.x = pk_rn(A[i].x, A[i].y); pk.y = pk_rn(A[i].z, A[i].w);
    pk.z = pk_rn(B[i].x, B[i].y); pk.w = pk_rn(B[i].z, B[i].w);
    smem[(i >> 1) * 1024 + rl * 8 + (c8 ^ (rl & 7))] = pk;
  }
  __syncthreads();

  const int cq = lane & 15, u = lane >> 4;

  // Q fragments from the chunk buffer holding this wave's 32 rows
  short8 qf[2][2];
  {
    const uint4* bq = &smem[(wu >> 2) * 1024];
    #pragma unroll
    for (int qs = 0; qs < 2; ++qs) {
      int rl = (wu & 3) * 32 + qs * 16 + cq;   // 0..127; rl&7 == cq&7
      #pragma unroll
      for (int ksd = 0; ksd < 2; ++ksd)
        qf[qs][ksd] = *(const short8*)&bq[rl * 8 + ((4 * ksd + u) ^ (cq & 7))];
    }
  }
  build_vt(smem, tid, 0);                      // VT(first) from buf0
  __syncthreads();

  floatx4 o[2][4];
  #pragma unroll
  for (int qs = 0; qs < 2; ++qs)
    #pragma unroll
    for (int nt = 0; nt < 4; ++nt) o[qs][nt] = (floatx4){0.f, 0.f, 0.f, 0.f};
  float l[2] = {0.f, 0.f};
  const float cf = 0.125f * 1.44269504088896340736f;  // scale * log2(e)

  unsigned short* Pw = (unsigned short*)&smem[3072 + wu * 128];
  const int pswz = u ^ (cq & 3);

  #pragma unroll
  for (int c = 0; c < 4; ++c) {
    // issue next-next chunk loads early; they drain under this chunk's compute
    float4 sA0, sB0, sA1, sB1;
    if (c < 2) {
      int ch = (first + c + 2) & 3;
      const float* src0 = xb + (size_t)(2 * (128 * ch + rr)) * DM + c8 * 8;
      sA0 = *(const float4*)src0;
      sB0 = *(const float4*)(src0 + 4);
      const float* src1 = xb + (size_t)(2 * (128 * ch + rr + 64)) * DM + c8 * 8;
      sA1 = *(const float4*)src1;
      sB1 = *(const float4*)(src1 + 4);
    }
    const uint4* kb = &smem[(c & 1) * 1024];

    #pragma unroll
    for (int ks = 0; ks < 4; ++ks) {
      // S^T strip: m = kk (32 rows), n = q (2 x 16)
      floatx4 acc[2][2];
      #pragma unroll
      for (int qs = 0; qs < 2; ++qs)
        #pragma unroll
        for (int t = 0; t < 2; ++t) acc[qs][t] = (floatx4){0.f, 0.f, 0.f, 0.f};
      #pragma unroll
      for (int t = 0; t < 2; ++t) {
        int r = 32 * ks + 16 * t + cq;         // chunk-local; r&7 == cq&7
        #pragma unroll
        for (int ksd = 0; ksd < 2; ++ksd) {
          short8 af = *(const short8*)&kb[r * 8 + ((4 * ksd + u) ^ (cq & 7))];
          #pragma unroll
          for (int qs = 0; qs < 2; ++qs)
            acc[qs][t] = __builtin_amdgcn_mfma_f32_16x16x32_bf16(af, qf[qs][ksd], acc[qs][t], 0, 0, 0);
        }
      }
      // V^T fragments (chunk-local u16)
      const int u16 = 4 * ks + u;
      short8 vfr[4];
      #pragma unroll
      for (int nt = 0; nt < 4; ++nt)
        vfr[nt] = *(const short8*)&smem[2048 + u16 * 64 + 16 * nt + (cq ^ (u16 & 7))];
      // exp + pack into per-wave P strip
      #pragma unroll
      for (int qs = 0; qs < 2; ++qs)
        #pragma unroll
        for (int t = 0; t < 2; ++t) {
          float p0 = __builtin_amdgcn_exp2f(acc[qs][t][0] * cf);
          float p1 = __builtin_amdgcn_exp2f(acc[qs][t][1] * cf);
          float p2 = __builtin_amdgcn_exp2f(acc[qs][t][2] * cf);
          float p3 = __builtin_amdgcn_exp2f(acc[qs][t][3] * cf);
          l[qs] += (p0 + p1) + (p2 + p3);
          uint2 w2;
          w2.x = pk_rn(p0, p1);
          w2.y = pk_rn(p2, p3);
          int unit = (qs * 16 + cq) * 4 + ((2 * t + (u >> 1)) ^ (cq & 3));
          *(uint2*)(Pw + unit * 8 + (u & 1) * 4) = w2;
        }
      // PV (own-wave P, no barrier)
      #pragma unroll
      for (int qs = 0; qs < 2; ++qs) {
        short8 pf = *(short8*)(Pw + ((qs * 16 + cq) * 4 + pswz) * 8);
        #pragma unroll
        for (int nt = 0; nt < 4; ++nt)
          o[qs][nt] = __builtin_amdgcn_mfma_f32_16x16x32_bf16(pf, vfr[nt], o[qs][nt], 0, 0, 0);
      }
    }

    if (c < 3) {
      __syncthreads();
      if (c < 2) {                             // deposit chunk c+2 into buf[c&1]
        uint4 p0, p1;
        p0.x = pk_rn(sA0.x, sA0.y); p0.y = pk_rn(sA0.z, sA0.w);
        p0.z = pk_rn(sB0.x, sB0.y); p0.w = pk_rn(sB0.z, sB0.w);
        p1.x = pk_rn(sA1.x, sA1.y); p1.y = pk_rn(sA1.z, sA1.w);
        p1.z = pk_rn(sB1.x, sB1.y); p1.w = pk_rn(sB1.z, sB1.w);
        uint4* kw = &smem[(c & 1) * 1024];
        kw[rr * 8 + (c8 ^ (rr & 7))] = p0;
        kw[(rr + 64) * 8 + (c8 ^ (rr & 7))] = p1;   // (rr+64)&7 == rr&7
      }
      build_vt(smem, tid, (c + 1) & 1);        // VT(c+1) from its stable buffer
      __syncthreads();
    }
  }

  // ---- softmax denominator + epilogue (O: col d = nt*16+cq, row q = 4u+r) ----
  #pragma unroll
  for (int qs = 0; qs < 2; ++qs) {
    float lf = l[qs];
    lf += __shfl_xor(lf, 16, 64);
    lf += __shfl_xor(lf, 32, 64);
    #pragma unroll
    for (int r = 0; r < 4; ++r) {
      float linv = 1.f / __shfl(lf, 4 * u + r, 64);
      int qrow = qoff + wu * 32 + qs * 16 + 4 * u + r;
      float* orow = ob + (size_t)(2 * qrow) * DM + cq;
      #pragma unroll
      for (int nt = 0; nt < 4; ++nt)
        orow[nt * 16] = o[qs][nt][r] * linv;
    }
  }
}

extern "C" void kernel_launch(void* const* d_in, const int* in_sizes, int n_in,
                              void* d_out, int out_size, void* d_ws, size_t ws_size,
                              hipStream_t stream) {
  const float* x = (const float*)d_in[0];
  float* out = (float*)d_out;
  fused2<<<dim3(1024), dim3(512), 0, stream>>>(x, out);
}